// Round 1
// baseline (169.590 us; speedup 1.0000x reference)
//
#include <hip/hip_runtime.h>
#include <hip/hip_bf16.h>

typedef __attribute__((ext_vector_type(8))) short bf16x8;
typedef __attribute__((ext_vector_type(4))) float f32x4;

#define NB    4096
#define NLINK 33
#define NJ    32
#define KTOT  1024
#define CJ    128
#define BM    128
#define BK    64

// round-to-nearest-even f32 -> bf16 (inputs are finite gaussians; NaN path not needed)
static __device__ __forceinline__ short f2bf(float f) {
    unsigned u = __builtin_bit_cast(unsigned, f);
    unsigned r = u + 0x7FFFu + ((u >> 16) & 1u);
    return (short)(r >> 16);
}

__global__ __launch_bounds__(256, 2) void joint_gemm(
    const float* __restrict__ link,
    const float* __restrict__ jf,
    const float* __restrict__ W,
    const float* __restrict__ bias,
    const int*   __restrict__ child,
    float* __restrict__ out)
{
    // fragment-ready LDS: [k/8][row] -> 8 contiguous bf16 along K (16B per cell)
    __shared__ bf16x8 lA[BK / 8][BM];  // 16 KB
    __shared__ bf16x8 lB[BK / 8][CJ];  // 16 KB

    const int tid  = threadIdx.x;
    const int lane = tid & 63;
    const int wave = tid >> 6;
    const int wr   = wave >> 1;   // 0..1 : wave row  (64 rows each)
    const int wc   = wave & 1;    // 0..1 : wave col  (64 cols each)

    const int bx = blockIdx.x;
    const int j  = bx & 31;       // joint (j-minor: neighbor blocks share A rows' locality window)
    const int mt = bx >> 5;       // m-tile
    const int rowbase = mt * BM;

    const int cidx = child[j];    // child link index (int32 per harness convention)

    // staging thread mapping
    const int am   = tid >> 3;    // 0..31 (A row within pass)
    const int aks  = tid & 7;     // 0..7  (A k-group of 8)
    const int bn   = tid & 127;   // 0..127 (B col)
    const int bks0 = tid >> 7;    // 0..1   (B k-group base within pass)

    const float* Wj = W + (size_t)j * KTOT * CJ;

    f32x4 acc[4][4] = {};         // 64 f32 accumulators

    float4 fa[4][2];              // A prefetch: 4 passes x 8 floats
    float  fb[4][8];              // B prefetch: 4 passes x 8 floats

    auto load_tile = [&](int k0) {
        #pragma unroll
        for (int p = 0; p < 4; ++p) {
            const int m = p * 32 + am;
            const float* ar = link + ((size_t)(rowbase + m) * NLINK + cidx) * KTOT + k0 + aks * 8;
            const float4* a4 = reinterpret_cast<const float4*>(ar);
            fa[p][0] = a4[0];
            fa[p][1] = a4[1];
            const float* br = Wj + (size_t)(k0 + (bks0 + p * 2) * 8) * CJ + bn;
            #pragma unroll
            for (int e = 0; e < 8; ++e) fb[p][e] = br[(size_t)e * CJ];
        }
    };

    load_tile(0);

    for (int t = 0; t < KTOT / BK; ++t) {
        __syncthreads();  // previous compute done reading LDS
        #pragma unroll
        for (int p = 0; p < 4; ++p) {
            const float* fsrc = reinterpret_cast<const float*>(&fa[p][0]);
            bf16x8 va, vb;
            #pragma unroll
            for (int e = 0; e < 8; ++e) va[e] = f2bf(fsrc[e]);
            lA[aks][p * 32 + am] = va;
            #pragma unroll
            for (int e = 0; e < 8; ++e) vb[e] = f2bf(fb[p][e]);
            lB[bks0 + p * 2][bn] = vb;
        }
        __syncthreads();  // tile visible

        if (t + 1 < KTOT / BK) load_tile((t + 1) * BK);  // next-tile loads in flight during MFMAs

        const int q = lane >> 4;
        const int r = lane & 15;
        #pragma unroll
        for (int kk = 0; kk < 2; ++kk) {
            bf16x8 af[4], bfr[4];
            #pragma unroll
            for (int mi = 0; mi < 4; ++mi) af[mi]  = lA[kk * 4 + q][wr * 64 + mi * 16 + r];
            #pragma unroll
            for (int ni = 0; ni < 4; ++ni) bfr[ni] = lB[kk * 4 + q][wc * 64 + ni * 16 + r];
            #pragma unroll
            for (int mi = 0; mi < 4; ++mi)
                #pragma unroll
                for (int ni = 0; ni < 4; ++ni)
                    acc[mi][ni] = __builtin_amdgcn_mfma_f32_16x16x32_bf16(
                        af[mi], bfr[ni], acc[mi][ni], 0, 0, 0);
        }
    }

    // epilogue: + bias + joint_feats, store
    const int q = lane >> 4;
    const int r = lane & 15;
    float bv[4];
    #pragma unroll
    for (int ni = 0; ni < 4; ++ni) bv[ni] = bias[j * CJ + wc * 64 + ni * 16 + r];

    #pragma unroll
    for (int mi = 0; mi < 4; ++mi) {
        #pragma unroll
        for (int rr = 0; rr < 4; ++rr) {
            const int bg = rowbase + wr * 64 + mi * 16 + q * 4 + rr;
            const size_t obase = ((size_t)bg * NJ + j) * CJ;
            #pragma unroll
            for (int ni = 0; ni < 4; ++ni) {
                const int o = wc * 64 + ni * 16 + r;
                out[obase + o] = acc[mi][ni][rr] + bv[ni] + jf[obase + o];
            }
        }
    }
}

extern "C" void kernel_launch(void* const* d_in, const int* in_sizes, int n_in,
                              void* d_out, int out_size, void* d_ws, size_t ws_size,
                              hipStream_t stream) {
    (void)in_sizes; (void)n_in; (void)out_size; (void)d_ws; (void)ws_size;
    const float* link  = (const float*)d_in[0];
    const float* jfeat = (const float*)d_in[1];
    const float* W     = (const float*)d_in[2];
    const float* bias  = (const float*)d_in[3];
    const int*   child = (const int*)d_in[4];
    float* out = (float*)d_out;

    dim3 grid(NJ * (NB / BM));   // 1024 blocks: j-minor, m-tile-major
    dim3 block(256);
    joint_gemm<<<grid, block, 0, stream>>>(link, jfeat, W, bias, child, out);
}